// Round 1
// baseline (12.869 us; speedup 1.0000x reference)
//
#include <hip/hip_runtime.h>

#define MARGIN 1.0f

// One wave (64 lanes) per batch row; 4 waves per block.
// Per row: stage nt-masked scores in LDS; each lane owns anchors i=lane and
// i=lane+64, loops j=0..127 reading the broadcast LDS value.
__global__ __launch_bounds__(256) void prl_partial(
    const float* __restrict__ scores,
    const int* __restrict__ top_mask,
    const int* __restrict__ valid_mask,
    float* __restrict__ ws_loss,
    unsigned int* __restrict__ ws_cnt)
{
    __shared__ float s_sh[4][128];
    __shared__ float red_loss[4];
    __shared__ unsigned int red_cnt[4];

    const int w    = threadIdx.x >> 6;
    const int lane = threadIdx.x & 63;
    const int row  = blockIdx.x * 4 + w;

    const float* srow = scores     + (size_t)row * 128;
    const int*   trow = top_mask   + (size_t)row * 128;
    const int*   vrow = valid_mask + (size_t)row * 128;

    const float s0 = srow[lane];
    const float s1 = srow[lane + 64];
    const int tm0 = trow[lane], tm1 = trow[lane + 64];
    const int vm0 = vrow[lane], vm1 = vrow[lane + 64];

    const bool top0 = (tm0 == 1), top1 = (tm1 == 1);
    const bool nt0  = (tm0 == 0) && (vm0 == 1);
    const bool nt1  = (tm1 == 0) && (vm1 == 1);

    // Fold the j-mask into the staged score: masked entries are -1e30 so
    // relu(pre + s'_j) == 0 without a separate multiply.
    s_sh[w][lane]      = nt0 ? s0 : -1e30f;
    s_sh[w][lane + 64] = nt1 ? s1 : -1e30f;
    __syncthreads();

    const float pre0 = MARGIN - s0;
    const float pre1 = MARGIN - s1;
    float acc0 = 0.f, acc1 = 0.f;
    #pragma unroll
    for (int j = 0; j < 128; ++j) {
        const float sj = s_sh[w][j];   // broadcast read: all lanes same addr
        acc0 += fmaxf(pre0 + sj, 0.f);
        acc1 += fmaxf(pre1 + sj, 0.f);
    }
    // The i-mask factors out of the j-sum.
    float lane_loss = (top0 ? acc0 : 0.f) + (top1 ? acc1 : 0.f);
    int lane_t  = (int)top0 + (int)top1;
    int lane_nt = (int)nt0  + (int)nt1;

    #pragma unroll
    for (int o = 32; o > 0; o >>= 1) {
        lane_loss += __shfl_xor(lane_loss, o, 64);
        lane_t    += __shfl_xor(lane_t,    o, 64);
        lane_nt   += __shfl_xor(lane_nt,   o, 64);
    }

    if (lane == 0) {
        red_loss[w] = lane_loss;
        red_cnt[w]  = (unsigned)(lane_t * lane_nt);  // exact pair count
    }
    __syncthreads();
    if (threadIdx.x == 0) {
        float bl = red_loss[0] + red_loss[1] + red_loss[2] + red_loss[3];
        unsigned bc = red_cnt[0] + red_cnt[1] + red_cnt[2] + red_cnt[3];
        ws_loss[blockIdx.x] = bl;
        ws_cnt[blockIdx.x]  = bc;
    }
}

// Single-block finisher: reduce 1024 partials in double, apply normalization.
__global__ __launch_bounds__(256) void prl_final(
    const float* __restrict__ ws_loss,
    const unsigned int* __restrict__ ws_cnt,
    float* __restrict__ out,
    int nblocks)
{
    const int tid = threadIdx.x;
    double l = 0.0;
    unsigned long long c = 0;
    for (int k = tid; k < nblocks; k += 256) {
        l += (double)ws_loss[k];
        c += (unsigned long long)ws_cnt[k];
    }
    #pragma unroll
    for (int o = 32; o > 0; o >>= 1) {
        l += __shfl_xor(l, o, 64);
        c += __shfl_xor(c, o, 64);
    }
    __shared__ double rl[4];
    __shared__ unsigned long long rc[4];
    const int w = tid >> 6, lane = tid & 63;
    if (lane == 0) { rl[w] = l; rc[w] = c; }
    __syncthreads();
    if (tid == 0) {
        double tl = rl[0] + rl[1] + rl[2] + rl[3];
        unsigned long long tc = rc[0] + rc[1] + rc[2] + rc[3];
        // reference: where(count>0, loss/max(count,1), loss)
        out[0] = (tc > 0) ? (float)(tl / (double)tc) : (float)tl;
    }
}

extern "C" void kernel_launch(void* const* d_in, const int* in_sizes, int n_in,
                              void* d_out, int out_size, void* d_ws, size_t ws_size,
                              hipStream_t stream) {
    const float* scores = (const float*)d_in[0];
    const int*   top    = (const int*)d_in[1];
    const int*   valid  = (const int*)d_in[2];

    const int batch = in_sizes[0] / 128;   // 4096
    const int nblocks = batch / 4;         // 1024 (one wave per row, 4 waves/block)

    float*        ws_loss = (float*)d_ws;
    unsigned int* ws_cnt  = (unsigned int*)((char*)d_ws + (size_t)nblocks * sizeof(float));

    prl_partial<<<nblocks, 256, 0, stream>>>(scores, top, valid, ws_loss, ws_cnt);
    prl_final<<<1, 256, 0, stream>>>(ws_loss, ws_cnt, (float*)d_out, nblocks);
}